// Round 5
// baseline (79.445 us; speedup 1.0000x reference)
//
#include <hip/hip_runtime.h>
#include <hip/hip_bf16.h>

// GaussianImage / Cholesky sum-rasterizer, T=3, N=2000, 256x256.
// Per-tile BINNING in preprocess (scatter expanded params into per-tile lists),
// so render reads only its own tile's ~15 survivors instead of scanning all
// 2000 gaussians in 8 sync'd chunks.
//
// k0: zero 768 tile counters (ws is poisoned 0xAA before every launch).
// k1: preprocess: poly-eval -> params; scatter (pos, conic+opac, color) into
//     every tile list the conservative bbox overlaps (atomic slot).
// k2: render: one LDS stage of the tile's list, one __syncthreads, FMA loop.

#define TFRAMES 3
#define NG      2000
#define HH      256
#define WW      256
#define NTX     16              // tiles per row (256/16)
#define NTILES  (NTX * NTX)     // 256 tiles per frame
#define LIST_CAP NG             // worst case: every gaussian in one tile -> no overflow
#define ALPHA_THRESH (1.0f / 255.0f)
#define ALPHA_CLAMP  0.999f

__device__ __forceinline__ float sigmoidf_(float x) { return 1.0f / (1.0f + expf(-x)); }

// ws layout (all offsets 16B-aligned):
//   counters: int  [T*NTILES]                     @ 0        (3072 B)
//   lpos:     float2[T*NTILES*LIST_CAP]           @ 4096     (12.288 MB)
//   lA:       float4[T*NTILES*LIST_CAP] (A,B,C,opac)         (24.576 MB)
//   lC:       float4[T*NTILES*LIST_CAP] (r,g,b,0)            (24.576 MB)
#define OFF_LPOS 4096
#define OFF_LA   (OFF_LPOS + (size_t)TFRAMES * NTILES * LIST_CAP * 8)
#define OFF_LC   (OFF_LA   + (size_t)TFRAMES * NTILES * LIST_CAP * 16)

__global__ void gs_zero(int* __restrict__ counters)
{
    int i = blockIdx.x * blockDim.x + threadIdx.x;
    if (i < TFRAMES * NTILES) counters[i] = 0;
}

__global__ void gs_preprocess(const float* __restrict__ xyz,
                              const float* __restrict__ chol,
                              const float* __restrict__ opc,
                              const float* __restrict__ feat,
                              int*    __restrict__ counters,
                              float2* __restrict__ lpos,
                              float4* __restrict__ lA,
                              float4* __restrict__ lC)
{
    int n = blockIdx.x * blockDim.x + threadIdx.x;
    if (n >= NG) return;

    float cxc[3], cyc[3], l1c[3], l2c[3], l3c[3], opcc[3];
#pragma unroll
    for (int d = 0; d < 3; ++d) {
        cxc[d]  = xyz[(d * NG + n) * 2 + 0];
        cyc[d]  = xyz[(d * NG + n) * 2 + 1];
        l1c[d]  = chol[(d * NG + n) * 3 + 0];
        l2c[d]  = chol[(d * NG + n) * 3 + 1];
        l3c[d]  = chol[(d * NG + n) * 3 + 2];
        opcc[d] = opc[d * NG + n];
    }
    float cr = sigmoidf_(feat[n * 3 + 0]);
    float cg = sigmoidf_(feat[n * 3 + 1]);
    float cb = sigmoidf_(feat[n * 3 + 2]);

#pragma unroll
    for (int t = 0; t < TFRAMES; ++t) {
        float tv = (float)t / (float)(TFRAMES - 1);   // 0, 0.5, 1
        // Horner == sum_d c[d]*t^d (poly eval at t; matches einsum with [1,t,t^2])
        float vx = fmaf(tv, fmaf(tv, cxc[2], cxc[1]), cxc[0]);
        float vy = fmaf(tv, fmaf(tv, cyc[2], cyc[1]), cyc[0]);
        float l1 = fmaf(tv, fmaf(tv, l1c[2], l1c[1]), l1c[0]) + 0.5f;
        float l2 = fmaf(tv, fmaf(tv, l2c[2], l2c[1]), l2c[0]);
        float l3 = fmaf(tv, fmaf(tv, l3c[2], l3c[1]), l3c[0]) + 0.5f;
        float po = fmaf(tv, fmaf(tv, opcc[2], opcc[1]), opcc[0]);

        float mx = 128.0f * (tanhf(vx) + 1.0f);   // 0.5*W*(x+1), W=H=256
        float my = 128.0f * (tanhf(vy) + 1.0f);

        // Sigma = L L^T, L=[[l1,0],[l2,l3]]
        float a = l1 * l1;
        float b = l1 * l2;
        float c = l2 * l2 + l3 * l3;
        float det = a * c - b * b;              // = (l1*l3)^2 >= 0
        float opa = sigmoidf_(po);

        if (!(det > 0.0f && det < 3.0e38f)) continue;   // degenerate: contributes 0
        float inv = 1.0f / det;
        float A = c * inv, B = -b * inv, C = a * inv;   // conic = Sigma^{-1}

        float s = opa * 255.0f;
        if (!(s > 1.0f)) continue;              // alpha can never reach 1/255
        // alpha >= 1/255 <=> q <= 2*ln(255*opac); inflate so rounding can never
        // EXCLUDE a pixel the reference includes (per-pixel test stays exact).
        float qm  = 2.0f * logf(s);
        float qmc = fmaf(qm, 1.0001f, 1e-3f);
        float rx = sqrtf(qmc * a);   // ellipse x-extent = sqrt(qm * Sigma_xx)
        float ry = sqrtf(qmc * c);   // ellipse y-extent = sqrt(qm * Sigma_yy)

        int xlo = (int)floorf(mx - rx), xhi = (int)ceilf(mx + rx);
        int ylo = (int)floorf(my - ry), yhi = (int)ceilf(my + ry);
        if (xhi < 0 || xlo > WW - 1 || yhi < 0 || ylo > HH - 1) continue;
        xlo = max(xlo, 0); xhi = min(xhi, WW - 1);
        ylo = max(ylo, 0); yhi = min(yhi, HH - 1);
        int tx0 = xlo >> 4, tx1 = xhi >> 4;
        int ty0 = ylo >> 4, ty1 = yhi >> 4;

        float2 pos = make_float2(mx, my);
        float4 gA  = make_float4(A, B, C, opa);
        float4 gC  = make_float4(cr, cg, cb, 0.0f);
        for (int ty = ty0; ty <= ty1; ++ty) {
            for (int tx = tx0; tx <= tx1; ++tx) {
                int tile = t * NTILES + ty * NTX + tx;
                int slot = atomicAdd(&counters[tile], 1);   // < LIST_CAP by construction
                size_t e = (size_t)tile * LIST_CAP + slot;
                lpos[e] = pos;
                lA[e]   = gA;
                lC[e]   = gC;
            }
        }
    }
}

__global__ __launch_bounds__(256) void gs_render(const int*    __restrict__ counters,
                                                 const float2* __restrict__ lpos,
                                                 const float4* __restrict__ lA,
                                                 const float4* __restrict__ lC,
                                                 float* __restrict__ out)
{
    const int tid = threadIdx.x;
    const int px  = (blockIdx.x << 4) + (tid & 15);
    const int py  = (blockIdx.y << 4) + (tid >> 4);
    const int t   = blockIdx.z;
    const int tile = t * NTILES + blockIdx.y * NTX + blockIdx.x;
    const size_t base = (size_t)tile * LIST_CAP;

    __shared__ float2 s_pos[256];
    __shared__ float4 s_A[256];
    __shared__ float4 s_C[256];

    const int cnt = counters[tile];
    float accr = 0.f, accg = 0.f, accb = 0.f;
    const float fx = (float)px, fy = (float)py;

    for (int b0 = 0; b0 < cnt; b0 += 256) {
        int m = min(cnt - b0, 256);
        if (tid < m) {
            s_pos[tid] = lpos[base + b0 + tid];
            s_A[tid]   = lA[base + b0 + tid];
            s_C[tid]   = lC[base + b0 + tid];
        }
        __syncthreads();
        for (int j = 0; j < m; ++j) {
            float2 p = s_pos[j];            // same-address broadcast: conflict-free
            float4 A = s_A[j];
            float dx = p.x - fx;
            float dy = p.y - fy;
            // q exactly as reference: a*dx^2 + 2b*dx*dy + c*dy^2, then exp(-0.5q)
            float q = A.x * dx * dx + 2.0f * A.y * dx * dy + A.z * dy * dy;
            float alpha = fminf(ALPHA_CLAMP, A.w * expf(-0.5f * q));
            float w = (alpha >= ALPHA_THRESH) ? alpha : 0.0f;   // kernel skip, branchless
            float4 col = s_C[j];
            accr = fmaf(w, col.x, accr);
            accg = fmaf(w, col.y, accg);
            accb = fmaf(w, col.z, accb);
        }
        __syncthreads();
    }

    // out[T,3,H,W]: final clip to [0,1] as in reference
    size_t o = (size_t)t * 3 * HH * WW + (size_t)py * WW + px;
    out[o]                        = fminf(fmaxf(accr, 0.f), 1.f);
    out[o + (size_t)HH * WW]      = fminf(fmaxf(accg, 0.f), 1.f);
    out[o + (size_t)2 * HH * WW]  = fminf(fmaxf(accb, 0.f), 1.f);
}

extern "C" void kernel_launch(void* const* d_in, const int* in_sizes, int n_in,
                              void* d_out, int out_size, void* d_ws, size_t ws_size,
                              hipStream_t stream)
{
    const float* xyz  = (const float*)d_in[0];   // [3, N, 2]
    const float* chol = (const float*)d_in[1];   // [3, N, 3]
    const float* opc  = (const float*)d_in[2];   // [3, N, 1]
    const float* feat = (const float*)d_in[3];   // [N, 3]
    float* out = (float*)d_out;                  // [T, 3, H, W] fp32

    char* ws = (char*)d_ws;
    int*    counters = (int*)ws;
    float2* lpos = (float2*)(ws + OFF_LPOS);
    float4* lA   = (float4*)(ws + OFF_LA);
    float4* lC   = (float4*)(ws + OFF_LC);

    gs_zero<<<dim3((TFRAMES * NTILES + 255) / 256), dim3(256), 0, stream>>>(counters);

    gs_preprocess<<<dim3((NG + 255) / 256), dim3(256), 0, stream>>>(
        xyz, chol, opc, feat, counters, lpos, lA, lC);

    gs_render<<<dim3(WW / 16, HH / 16, TFRAMES), dim3(256), 0, stream>>>(
        counters, lpos, lA, lC, out);
}

// Round 6
// 76.987 us; speedup vs baseline: 1.0319x; 1.0319x over previous
//
#include <hip/hip_runtime.h>
#include <hip/hip_bf16.h>

// GaussianImage / Cholesky sum-rasterizer, T=3, N=2000, 256x256.
// Round 5 -> 6: ONE fused kernel (no workspace, no multi-node graph).
// Evidence: 3-node binned (79.4us) LOST to 2-node full-scan (72.9us); both
// dominated by fixed costs (256MiB harness poison-fill ~41us + per-node
// overhead). So minimize node count: each 16x16 tile-block re-derives
// per-gaussian params from the raw 56KB inputs (L2-resident), culls with a
// fixed conservative q<=11.1 bound (2*ln(255*opac) <= 2*ln255 = 11.083 for
// opac<1 -- no logf needed), compacts survivors to LDS, then accumulates.
// Exact per-pixel alpha>=1/255 test unchanged vs reference.

#define TFRAMES 3
#define NG      2000
#define HH      256
#define WW      256
#define ALPHA_THRESH (1.0f / 255.0f)
#define ALPHA_CLAMP  0.999f
#define QMAX 11.1f   // > 2*ln(255) = 11.0832, conservative for any opac < 1

__device__ __forceinline__ float sigmoidf_(float x) { return 1.0f / (1.0f + expf(-x)); }

__global__ __launch_bounds__(256) void gs_fused(const float* __restrict__ xyz,
                                                const float* __restrict__ chol,
                                                const float* __restrict__ opc,
                                                const float* __restrict__ feat,
                                                float* __restrict__ out)
{
    const int tid = threadIdx.x;
    const int px  = (blockIdx.x << 4) + (tid & 15);
    const int py  = (blockIdx.y << 4) + (tid >> 4);
    const int t   = blockIdx.z;
    const float tv = 0.5f * (float)t;              // t in {0, 0.5, 1}

    // tile pixel-coordinate bounds (pixel centers at integers), small margin
    const float bx0 = (float)(blockIdx.x << 4) - 0.01f;
    const float bx1 = (float)(blockIdx.x << 4) + 15.01f;
    const float by0 = (float)(blockIdx.y << 4) - 0.01f;
    const float by1 = (float)(blockIdx.y << 4) + 15.01f;

    __shared__ int    s_cnt;
    __shared__ float2 s_pos[256];
    __shared__ float4 s_A[256];   // conic A,B,C + opac
    __shared__ float4 s_C[256];   // color r,g,b

    float accr = 0.f, accg = 0.f, accb = 0.f;
    const float fx = (float)px, fy = (float)py;

    for (int base = 0; base < NG; base += 256) {   // 8 chunks
        if (tid == 0) s_cnt = 0;
        __syncthreads();

        int g = base + tid;
        if (g < NG) {
            // ---- inline preprocess for gaussian g at frame t ----
            // xyz_coeffs [3][N][2]
            float x0 = xyz[g * 2 + 0],            y0 = xyz[g * 2 + 1];
            float x1 = xyz[(NG + g) * 2 + 0],     y1 = xyz[(NG + g) * 2 + 1];
            float x2 = xyz[(2 * NG + g) * 2 + 0], y2 = xyz[(2 * NG + g) * 2 + 1];
            float vx = fmaf(tv, fmaf(tv, x2, x1), x0);
            float vy = fmaf(tv, fmaf(tv, y2, y1), y0);
            // cholesky_coeffs [3][N][3] + bound [0.5, 0, 0.5]
            float l1 = fmaf(tv, fmaf(tv, chol[(2 * NG + g) * 3 + 0], chol[(NG + g) * 3 + 0]), chol[g * 3 + 0]) + 0.5f;
            float l2 = fmaf(tv, fmaf(tv, chol[(2 * NG + g) * 3 + 1], chol[(NG + g) * 3 + 1]), chol[g * 3 + 1]);
            float l3 = fmaf(tv, fmaf(tv, chol[(2 * NG + g) * 3 + 2], chol[(NG + g) * 3 + 2]), chol[g * 3 + 2]) + 0.5f;
            // opacity_coeffs [3][N][1]
            float po = fmaf(tv, fmaf(tv, opc[2 * NG + g], opc[NG + g]), opc[g]);

            float mx = 128.0f * (tanhf(vx) + 1.0f);   // 0.5*W*(x+1)
            float my = 128.0f * (tanhf(vy) + 1.0f);

            float a = l1 * l1;                    // Sigma_xx
            float b = l1 * l2;
            float c = l2 * l2 + l3 * l3;          // Sigma_yy
            float det = a * c - b * b;            // = (l1*l3)^2
            float opa = sigmoidf_(po);

            bool ok = (det > 0.0f) && (det < 3.0e38f) && (opa * 255.0f > 1.0f);
            if (ok) {
                // alpha>=1/255 requires q <= 2*ln(255*opa) <= QMAX; ellipse
                // extent along x/y: sqrt(q * Sigma_xx/yy). Conservative bbox.
                float rx = sqrtf(QMAX * a);
                float ry = sqrtf(QMAX * c);
                ok = (mx + rx >= bx0) && (mx - rx <= bx1) &&
                     (my + ry >= by0) && (my - ry <= by1);
            }
            if (ok) {
                float inv = 1.0f / det;
                int k = atomicAdd(&s_cnt, 1);     // <=256 writers, no overflow
                s_pos[k] = make_float2(mx, my);
                s_A[k]   = make_float4(c * inv, -b * inv, a * inv, opa);
                s_C[k]   = make_float4(sigmoidf_(feat[g * 3 + 0]),
                                       sigmoidf_(feat[g * 3 + 1]),
                                       sigmoidf_(feat[g * 3 + 2]), 0.0f);
            }
        }
        __syncthreads();

        int cnt = s_cnt;
        for (int j = 0; j < cnt; ++j) {
            float2 p = s_pos[j];          // same-address LDS broadcast, conflict-free
            float4 A = s_A[j];
            float dx = p.x - fx;
            float dy = p.y - fy;
            // q exactly as reference: a*dx^2 + 2b*dx*dy + c*dy^2, then exp(-0.5q)
            float q = A.x * dx * dx + 2.0f * A.y * dx * dy + A.z * dy * dy;
            float alpha = fminf(ALPHA_CLAMP, A.w * expf(-0.5f * q));
            float w = (alpha >= ALPHA_THRESH) ? alpha : 0.0f;   // exact kernel-skip
            float4 col = s_C[j];
            accr = fmaf(w, col.x, accr);
            accg = fmaf(w, col.y, accg);
            accb = fmaf(w, col.z, accb);
        }
        __syncthreads();   // protect LDS before next chunk overwrites
    }

    // out[T,3,H,W], clip to [0,1] as in reference
    size_t o = (size_t)t * 3 * HH * WW + (size_t)py * WW + px;
    out[o]                        = fminf(fmaxf(accr, 0.f), 1.f);
    out[o + (size_t)HH * WW]      = fminf(fmaxf(accg, 0.f), 1.f);
    out[o + (size_t)2 * HH * WW]  = fminf(fmaxf(accb, 0.f), 1.f);
}

extern "C" void kernel_launch(void* const* d_in, const int* in_sizes, int n_in,
                              void* d_out, int out_size, void* d_ws, size_t ws_size,
                              hipStream_t stream)
{
    const float* xyz  = (const float*)d_in[0];   // [3, N, 2]
    const float* chol = (const float*)d_in[1];   // [3, N, 3]
    const float* opc  = (const float*)d_in[2];   // [3, N, 1]
    const float* feat = (const float*)d_in[3];   // [N, 3]
    float* out = (float*)d_out;                  // [T, 3, H, W] fp32

    gs_fused<<<dim3(WW / 16, HH / 16, TFRAMES), dim3(256), 0, stream>>>(
        xyz, chol, opc, feat, out);
}

// Round 7
// 74.758 us; speedup vs baseline: 1.0627x; 1.0298x over previous
//
#include <hip/hip_runtime.h>
#include <hip/hip_bf16.h>

// GaussianImage / Cholesky sum-rasterizer, T=3, N=2000, 256x256.
// Round 6 -> 7: back to the best-measured 2-node structure (preprocess once,
// render scans cheap precomputed float4s), with render barriers cut from 24
// to ~4: register scan of 8 cull records/thread -> local survivor list ->
// ONE atomicAdd reserving a contiguous LDS index range -> single stage pass.
// Evidence: 2-node full-scan 72.9us < 1-node fused 77.0us < 3-node binned
// 79.4us; spread is the ~5-10us controllable kernel slice of a fixed ~70us
// window (256MiB harness poison fill ~41us + replay overhead).

#define TFRAMES 3
#define NG      2000
#define HH      256
#define WW      256
#define ALPHA_THRESH (1.0f / 255.0f)
#define ALPHA_CLAMP  0.999f

__device__ __forceinline__ float sigmoidf_(float x) { return 1.0f / (1.0f + expf(-x)); }

// ws: cull float4[T*NG] @0 ; g1 float4[T*NG] @96KB ; g2 float4[T*NG] @192KB
#define OFF_G1 98304
#define OFF_G2 196608

__global__ void gs_preprocess(const float* __restrict__ xyz,
                              const float* __restrict__ chol,
                              const float* __restrict__ opc,
                              const float* __restrict__ feat,
                              float4* __restrict__ cull,
                              float4* __restrict__ g1,
                              float4* __restrict__ g2)
{
    int n = blockIdx.x * blockDim.x + threadIdx.x;
    if (n >= NG) return;

    float cxc[3], cyc[3], l1c[3], l2c[3], l3c[3], opcc[3];
#pragma unroll
    for (int d = 0; d < 3; ++d) {
        cxc[d]  = xyz[(d * NG + n) * 2 + 0];
        cyc[d]  = xyz[(d * NG + n) * 2 + 1];
        l1c[d]  = chol[(d * NG + n) * 3 + 0];
        l2c[d]  = chol[(d * NG + n) * 3 + 1];
        l3c[d]  = chol[(d * NG + n) * 3 + 2];
        opcc[d] = opc[d * NG + n];
    }
    float cr = sigmoidf_(feat[n * 3 + 0]);
    float cg = sigmoidf_(feat[n * 3 + 1]);
    float cb = sigmoidf_(feat[n * 3 + 2]);

#pragma unroll
    for (int t = 0; t < TFRAMES; ++t) {
        float tv = 0.5f * (float)t;                    // t in {0, 0.5, 1}
        float vx = fmaf(tv, fmaf(tv, cxc[2], cxc[1]), cxc[0]);
        float vy = fmaf(tv, fmaf(tv, cyc[2], cyc[1]), cyc[0]);
        float l1 = fmaf(tv, fmaf(tv, l1c[2], l1c[1]), l1c[0]) + 0.5f;
        float l2 = fmaf(tv, fmaf(tv, l2c[2], l2c[1]), l2c[0]);
        float l3 = fmaf(tv, fmaf(tv, l3c[2], l3c[1]), l3c[0]) + 0.5f;
        float po = fmaf(tv, fmaf(tv, opcc[2], opcc[1]), opcc[0]);

        float mx = 128.0f * (tanhf(vx) + 1.0f);        // 0.5*W*(x+1)
        float my = 128.0f * (tanhf(vy) + 1.0f);

        // Sigma = L L^T, L=[[l1,0],[l2,l3]]
        float a = l1 * l1;
        float b = l1 * l2;
        float c = l2 * l2 + l3 * l3;
        float det = a * c - b * b;                     // = (l1*l3)^2
        float opa = sigmoidf_(po);

        float rx = -1.0e9f, ry = -1.0e9f;              // default: never overlaps
        float A = 0.f, B = 0.f, C = 0.f;
        if (det > 0.0f && det < 3.0e38f) {
            float inv = 1.0f / det;
            A = c * inv; B = -b * inv; C = a * inv;    // conic = Sigma^{-1}
            float s = opa * 255.0f;
            if (s > 1.0f) {
                // alpha >= 1/255 <=> q <= 2*ln(255*opac); inflate so rounding
                // can never EXCLUDE a pixel the reference includes.
                float qm  = 2.0f * logf(s);
                float qmc = fmaf(qm, 1.0001f, 1e-3f);
                rx = sqrtf(qmc * a);                   // sqrt(qm * Sigma_xx)
                ry = sqrtf(qmc * c);
            }
        }
        int idx = t * NG + n;
        cull[idx] = make_float4(mx, my, rx, ry);
        g1[idx]   = make_float4(A, B, C, opa);
        g2[idx]   = make_float4(cr, cg, cb, 0.0f);
    }
}

__global__ __launch_bounds__(256) void gs_render(const float4* __restrict__ cull,
                                                 const float4* __restrict__ g1,
                                                 const float4* __restrict__ g2,
                                                 float* __restrict__ out)
{
    const int tid = threadIdx.x;
    const int px  = (blockIdx.x << 4) + (tid & 15);
    const int py  = (blockIdx.y << 4) + (tid >> 4);
    const int t   = blockIdx.z;
    const float tcx = (float)(blockIdx.x << 4) + 7.5f;   // tile center
    const float tcy = (float)(blockIdx.y << 4) + 7.5f;

    __shared__ int    s_cnt;
    __shared__ int    s_idx[2048];      // worst case: all NG survive (8 KB)
    __shared__ float4 s_P[256];         // pos in .xy
    __shared__ float4 s_A[256];         // conic A,B,C + opac
    __shared__ float4 s_C[256];         // color

    const float4* __restrict__ cu = cull + t * NG;
    const float4* __restrict__ gA = g1   + t * NG;
    const float4* __restrict__ gC = g2   + t * NG;

    // ---- phase 1: register scan, 8 coalesced float4 loads per thread ----
    int loc[8];
    int nl = 0;
#pragma unroll
    for (int i = 0; i < 8; ++i) {
        int g = i * 256 + tid;
        if (g < NG) {
            float4 c4 = cu[g];
            // conservative tile/bbox overlap (pixels at integer coords)
            if (fabsf(c4.x - tcx) <= c4.z + 7.51f &&
                fabsf(c4.y - tcy) <= c4.w + 7.51f)
                loc[nl++] = g;
        }
    }

    if (tid == 0) s_cnt = 0;
    __syncthreads();
    int slot = (nl > 0) ? atomicAdd(&s_cnt, nl) : 0;   // ONE atomic per thread
    for (int k = 0; k < nl; ++k) s_idx[slot + k] = loc[k];
    __syncthreads();

    const int cnt = s_cnt;
    float accr = 0.f, accg = 0.f, accb = 0.f;
    const float fx = (float)px, fy = (float)py;

    // ---- phase 2: stage survivors to LDS, accumulate (1 chunk expected) ----
    for (int b0 = 0; b0 < cnt; b0 += 256) {
        int m = min(cnt - b0, 256);
        if (tid < m) {
            int idx = s_idx[b0 + tid];
            s_P[tid] = cu[idx];
            s_A[tid] = gA[idx];
            s_C[tid] = gC[idx];
        }
        __syncthreads();
        for (int j = 0; j < m; ++j) {
            float4 P = s_P[j];          // same-address LDS broadcast, conflict-free
            float4 A = s_A[j];
            float dx = P.x - fx;
            float dy = P.y - fy;
            // q exactly as reference: a*dx^2 + 2b*dx*dy + c*dy^2, then exp(-0.5q)
            float q = A.x * dx * dx + 2.0f * A.y * dx * dy + A.z * dy * dy;
            float alpha = fminf(ALPHA_CLAMP, A.w * expf(-0.5f * q));
            float w = (alpha >= ALPHA_THRESH) ? alpha : 0.0f;   // exact kernel-skip
            float4 col = s_C[j];
            accr = fmaf(w, col.x, accr);
            accg = fmaf(w, col.y, accg);
            accb = fmaf(w, col.z, accb);
        }
        __syncthreads();
    }

    // out[T,3,H,W], clip to [0,1] as in reference
    size_t o = (size_t)t * 3 * HH * WW + (size_t)py * WW + px;
    out[o]                        = fminf(fmaxf(accr, 0.f), 1.f);
    out[o + (size_t)HH * WW]      = fminf(fmaxf(accg, 0.f), 1.f);
    out[o + (size_t)2 * HH * WW]  = fminf(fmaxf(accb, 0.f), 1.f);
}

extern "C" void kernel_launch(void* const* d_in, const int* in_sizes, int n_in,
                              void* d_out, int out_size, void* d_ws, size_t ws_size,
                              hipStream_t stream)
{
    const float* xyz  = (const float*)d_in[0];   // [3, N, 2]
    const float* chol = (const float*)d_in[1];   // [3, N, 3]
    const float* opc  = (const float*)d_in[2];   // [3, N, 1]
    const float* feat = (const float*)d_in[3];   // [N, 3]
    float* out = (float*)d_out;                  // [T, 3, H, W] fp32

    char* ws = (char*)d_ws;
    float4* cull = (float4*)(ws);
    float4* g1   = (float4*)(ws + OFF_G1);
    float4* g2   = (float4*)(ws + OFF_G2);

    gs_preprocess<<<dim3((NG + 255) / 256), dim3(256), 0, stream>>>(
        xyz, chol, opc, feat, cull, g1, g2);

    gs_render<<<dim3(WW / 16, HH / 16, TFRAMES), dim3(256), 0, stream>>>(
        cull, g1, g2, out);
}